// Round 10
// baseline (258.126 us; speedup 1.0000x reference)
//
#include <hip/hip_runtime.h>

// PointTransformerLayer fused kernel for MI355X (gfx950) — round 9 design
// (resubmit; round-9 bench was an infra failure: container failed twice, no
// counters — same signature as round 3 which passed cleanly on resubmit).
// vs r8 (104us main, all pipes <35%, 9 barrier phases => serialization-bound):
//  * j-tile wave ownership: wave w owns j = w*32..w*32+31. Every C-fragment is
//    converted to the next GEMM's B-fragment IN REGISTERS via
//    v_permlane32_swap_b32 (half-wave row-group exchange). No staging LDS,
//    no bank conflicts, ONE barrier total (2KB epilogue combine).
//  * X1 built per-lane in registers (coalesced pos loads).
//  * aux qkv: 128 blocks x 32 rows, weight row in VGPRs, 2-way ILP.
// Weights single bf16 (r8: absmax 0.0156 = r4's, threshold 0.088).
// ws: qkv@0 (3145728), fW1@3145728 (6144), fW2@3151872 (8192),
//     fA1@3160064 (32768), fA2@3192832 (32768); end 3225600 B.

typedef short short8 __attribute__((ext_vector_type(8)));
typedef float f32x4 __attribute__((ext_vector_type(4)));
typedef float f32x16 __attribute__((ext_vector_type(16)));
typedef unsigned int u32x4 __attribute__((ext_vector_type(4)));

union frag_u { short8 s; u32x4 u; };

__device__ __forceinline__ unsigned short f2bf(float x) {
  union { float f; unsigned int u; } a; a.f = x;
  unsigned int r = a.u + 0x7fffu + ((a.u >> 16) & 1u);  // RNE
  return (unsigned short)(r >> 16);
}
__device__ __forceinline__ unsigned int pk2(float a, float b) {  // a->lo16, b->hi16
  unsigned int r;
  asm("v_cvt_pk_bf16_f32 %0, %1, %2" : "=v"(r) : "v"(a), "v"(b));
  return r;
}

// ---------------- aux: qkv GEMM + single-plane weight A-frags ----------------
// A-frag (32x32x16): lane l holds A[row = mt*32 + (l&31)][k = kc*16 + (l>>5)*8 + e].
__device__ __forceinline__ void fill_frag(unsigned short* dst,
    const float* src, int Ksrc, int KC, int idx) {
  int e = idx & 7;
  int lane = (idx >> 3) & 63;
  int kc = (idx >> 9) % KC;
  int mt = idx / (512 * KC);
  int row = mt * 32 + (lane & 31);
  int k = kc * 16 + ((lane >> 5) << 3) + e;
  float v = (k < Ksrc) ? src[row * Ksrc + k] : 0.0f;
  dst[idx] = f2bf(v);
}

#define QKV_BLOCKS 128  // (bt 32) x (n-quarter 4), 32 rows each

__global__ void aux_kernel(const float* __restrict__ wqkv,
    const float* __restrict__ pw1, const float* __restrict__ pw2,
    const float* __restrict__ aw1, const float* __restrict__ aw2,
    const float* __restrict__ x,
    unsigned short* __restrict__ fW1, unsigned short* __restrict__ fW2,
    unsigned short* __restrict__ fA1, unsigned short* __restrict__ fA2,
    float* __restrict__ qkv) {
  int tid = threadIdx.x;
  if (blockIdx.x < QKV_BLOCKS) {  // ---- qkv: 32 rows of x per block ----
    __shared__ float xs[32 * 64];
    int bt = blockIdx.x >> 2, nq = blockIdx.x & 3;
    const float* xb = x + (bt * 128 + nq * 32) * 64;
#pragma unroll
    for (int o = 0; o < 8; ++o) xs[tid + o * 256] = xb[tid + o * 256];
    __syncthreads();
    if (tid < 192) {
      const float* wr_g = wqkv + tid * 64;
      float wr[64];
#pragma unroll
      for (int k = 0; k < 64; ++k) wr[k] = wr_g[k];
      float* qb = qkv + (size_t)(bt * 128 + nq * 32) * 192 + tid;
      for (int n = 0; n < 32; n += 2) {  // 2-way ILP
        float a0 = 0.f, a1 = 0.f;
#pragma unroll
        for (int k = 0; k < 64; ++k) {
          a0 += xs[n * 64 + k] * wr[k];
          a1 += xs[n * 64 + 64 + k] * wr[k];
        }
        qb[n * 192] = a0;
        qb[n * 192 + 192] = a1;
      }
    }
    return;
  }
  int gid = (blockIdx.x - QKV_BLOCKS) * 256 + tid;  // 39936 frag elems
  if (gid < 3072) { fill_frag(fW1, pw1, 34, 3, gid); return; }    // [64][34->48]
  gid -= 3072;
  if (gid < 4096) { fill_frag(fW2, pw2, 64, 4, gid); return; }    // [64][64]
  gid -= 4096;
  if (gid < 16384) { fill_frag(fA1, aw1, 64, 4, gid); return; }   // [256][64]
  gid -= 16384;
  fill_frag(fA2, aw2, 256, 16, gid);                              // [64][256]
}

// ---------------- main fused kernel ----------------
// C/D layout 32x32: col = l&31, row = (r&3) + 8*(r>>2) + 4*(l>>5).
// B-frag: lane l holds B[k = (l>>5)*8 + e][col = l&31], e = 0..7.
__device__ __forceinline__ f32x16 ld16(const float* p, int l) {
  f32x16 r;
#pragma unroll
  for (int q = 0; q < 4; ++q) {
    f32x4 v = *(const f32x4*)(p + 8 * q + ((l >> 5) << 2));
#pragma unroll
    for (int s = 0; s < 4; ++s) r[4 * q + s] = v[s];
  }
  return r;
}

// C-frag (32 rows = 2 k-chunks of 16) -> 2 B-frags, in-register.
// v_permlane32_swap_b32 vdst,vsrc: upper 32 lanes of vdst <-> lower 32 of vsrc.
//   u0=pk2(c0,c1) u1=pk2(c2,c3) u2=pk2(c4,c5) u3=pk2(c6,c7)
//   (rows (0,1),(2,3),(8,9),(10,11) + 4*h5)
//   swap(u0,u2): u0 -> rows (0,1)|(8,9) = e0,1 ; u2 -> rows (4,5)|(12,13) = e4,5
//   swap(u1,u3): u1 -> e2,3 ; u3 -> e6,7.
__device__ __forceinline__ void c2b(f32x16 c, short8* out, bool relu) {
#pragma unroll
  for (int kk = 0; kk < 2; ++kk) {
    float a0 = c[8*kk+0], a1 = c[8*kk+1], a2 = c[8*kk+2], a3 = c[8*kk+3];
    float a4 = c[8*kk+4], a5 = c[8*kk+5], a6 = c[8*kk+6], a7 = c[8*kk+7];
    if (relu) {
      a0 = fmaxf(a0, 0.f); a1 = fmaxf(a1, 0.f); a2 = fmaxf(a2, 0.f); a3 = fmaxf(a3, 0.f);
      a4 = fmaxf(a4, 0.f); a5 = fmaxf(a5, 0.f); a6 = fmaxf(a6, 0.f); a7 = fmaxf(a7, 0.f);
    }
    unsigned u0 = pk2(a0, a1), u1 = pk2(a2, a3), u2 = pk2(a4, a5), u3 = pk2(a6, a7);
    asm("v_permlane32_swap_b32 %0, %1" : "+v"(u0), "+v"(u2));
    asm("v_permlane32_swap_b32 %0, %1" : "+v"(u1), "+v"(u3));
    frag_u fu; fu.u[0] = u0; fu.u[1] = u1; fu.u[2] = u2; fu.u[3] = u3;
    out[kk] = fu.s;
  }
}

#define MFMA32(acc, av, bv) \
  acc = __builtin_amdgcn_mfma_f32_32x32x16_bf16(av, bv, acc, 0, 0, 0)
#define AF(ptr, idx) (*(const short8*)((ptr) + (size_t)(idx) * 512 + (size_t)l * 8))

__global__ __launch_bounds__(256, 3) void main_kernel(
    const float* __restrict__ pos, const float* __restrict__ qkv,
    const unsigned short* __restrict__ fW1, const unsigned short* __restrict__ fW2,
    const unsigned short* __restrict__ fA1, const unsigned short* __restrict__ fA2,
    const float* __restrict__ pb1, const float* __restrict__ pb2,
    const float* __restrict__ ab1, const float* __restrict__ ab2,
    float* __restrict__ out) {
  __shared__ float red[512];  // [wave][pd 64 | pn 64]
  const int i = blockIdx.x, bt = blockIdx.y;
  const int tid = threadIdx.x;
  const int w = tid >> 6, l = tid & 63;     // wave w owns j-tile w
  const int lc = l & 31, h5 = l >> 5;
  const int j = w * 32 + lc;

  // ---- X1 B-frags in registers: f = c*17+jj (34 real, 48 padded) ----
  short8 x1f[3];
#pragma unroll
  for (int kc = 0; kc < 3; ++kc) {
    frag_u fu;
#pragma unroll
    for (int wo = 0; wo < 4; ++wo) {
      float v0 = 0.f, v1 = 0.f;
      int f0 = kc * 16 + h5 * 8 + 2 * wo;
      if (f0 < 34) {
        int c = (f0 >= 17) ? 1 : 0;
        const float* ps = pos + (((bt * 17 + (f0 - 17 * c)) * 3 + c) << 7);
        v0 = ps[i] - ps[j];
      }
      int f1 = f0 + 1;
      if (f1 < 34) {
        int c = (f1 >= 17) ? 1 : 0;
        const float* ps = pos + (((bt * 17 + (f1 - 17 * c)) * 3 + c) << 7);
        v1 = ps[i] - ps[j];
      }
      fu.u[wo] = pk2(v0, v1);
    }
    x1f[kc] = fu.s;
  }

  // ---- G1: H1 = relu(W1 @ X1^T + b1), C-frags -> B-frags in-register ----
  short8 h1b[4];
#pragma unroll
  for (int mt = 0; mt < 2; ++mt) {
    f32x16 acc = ld16(pb1 + mt * 32, l);
#pragma unroll
    for (int kc = 0; kc < 3; ++kc) MFMA32(acc, AF(fW1, mt * 3 + kc), x1f[kc]);
    c2b(acc, &h1b[2 * mt], true);
  }

  // ---- G2 + E-stage: E = W2 @ H1^T + b2; U/vp in-register ----
  unsigned vpk[16];
  short8 ub[4];
  const float* qkv_bt = qkv + (size_t)(bt * 128) * 192;
  const float* rp = qkv_bt + j * 192;
#pragma unroll
  for (int mt = 0; mt < 2; ++mt) {
    f32x16 e = ld16(pb2 + mt * 32, l);
#pragma unroll
    for (int kc = 0; kc < 4; ++kc) MFMA32(e, AF(fW2, mt * 4 + kc), h1b[kc]);
    f32x16 qv = ld16(qkv_bt + i * 192 + mt * 32, l);
    f32x16 kk = ld16(rp + 64 + mt * 32, l);
    f32x16 vv = ld16(rp + 128 + mt * 32, l);
    f32x16 u;
#pragma unroll
    for (int r = 0; r < 16; ++r) u[r] = qv[r] - kk[r] + e[r];
#pragma unroll
    for (int s = 0; s < 8; ++s)
      vpk[mt * 8 + s] = pk2(vv[2 * s] + e[2 * s], vv[2 * s + 1] + e[2 * s + 1]);
    c2b(u, &ub[2 * mt], false);
  }

  // ---- G3/G4 over 4 h-chunks of 64: all in-register, no barriers ----
  f32x16 s0 = ld16(ab2, l), s1 = ld16(ab2 + 32, l);
#pragma unroll 1
  for (int hc = 0; hc < 4; ++hc) {
    short8 h2b[4];
#pragma unroll
    for (int mt = 0; mt < 2; ++mt) {  // G3: H2c = relu(A1c @ U^T + b1c)
      f32x16 h = ld16(ab1 + hc * 64 + mt * 32, l);
#pragma unroll
      for (int kc = 0; kc < 4; ++kc) MFMA32(h, AF(fA1, (hc * 2 + mt) * 4 + kc), ub[kc]);
      c2b(h, &h2b[2 * mt], true);
    }
#pragma unroll
    for (int kc = 0; kc < 4; ++kc) {  // G4: S += A2c @ H2c^T
      MFMA32(s0, AF(fA2, hc * 4 + kc), h2b[kc]);
      MFMA32(s1, AF(fA2, 16 + hc * 4 + kc), h2b[kc]);
    }
  }

  // ---- epilogue: softmax over j (exp-safe) + weighted vp sum ----
#pragma unroll
  for (int mt = 0; mt < 2; ++mt) {
    f32x16 sc = mt ? s1 : s0;
#pragma unroll
    for (int pi = 0; pi < 8; ++pi) {
      int r0 = 2 * pi;
      float x0 = __expf(sc[r0]), x1 = __expf(sc[r0 + 1]);
      unsigned pv = vpk[mt * 8 + pi];
      float v0 = __uint_as_float(pv << 16);
      float v1 = __uint_as_float(pv & 0xffff0000u);
      float pd0 = x0, pn0 = x0 * v0;
      float pd1 = x1, pn1 = x1 * v1;
#pragma unroll
      for (int m = 1; m <= 16; m <<= 1) {
        pd0 += __shfl_xor(pd0, m); pn0 += __shfl_xor(pn0, m);
        pd1 += __shfl_xor(pd1, m); pn1 += __shfl_xor(pn1, m);
      }
      if (lc == 0) {
        int d0 = mt * 32 + (r0 & 3) + 8 * (r0 >> 2) + 4 * h5;
        red[w * 128 + d0] = pd0;          red[w * 128 + 64 + d0] = pn0;
        red[w * 128 + d0 + 1] = pd1;      red[w * 128 + 64 + d0 + 1] = pn1;
      }
    }
  }
  __syncthreads();
  if (tid < 64) {
    float den = red[tid] + red[128 + tid] + red[256 + tid] + red[384 + tid];
    float num = red[64 + tid] + red[192 + tid] + red[320 + tid] + red[448 + tid];
    out[(bt * 128 + i) * 64 + tid] = num / den;
  }
}

extern "C" void kernel_launch(void* const* d_in, const int* in_sizes, int n_in,
                              void* d_out, int out_size, void* d_ws, size_t ws_size,
                              hipStream_t stream) {
  const float* x    = (const float*)d_in[0];
  const float* pos  = (const float*)d_in[1];
  const float* wqkv = (const float*)d_in[2];
  const float* pw1  = (const float*)d_in[3];
  const float* pb1  = (const float*)d_in[4];
  const float* pw2  = (const float*)d_in[5];
  const float* pb2  = (const float*)d_in[6];
  const float* aw1  = (const float*)d_in[7];
  const float* ab1  = (const float*)d_in[8];
  const float* aw2  = (const float*)d_in[9];
  const float* ab2  = (const float*)d_in[10];
  float* out = (float*)d_out;
  char* ws = (char*)d_ws;

  float* qkv = (float*)ws;                               // 3145728 B
  unsigned short* fW1 = (unsigned short*)(ws + 3145728); // 6144 B
  unsigned short* fW2 = (unsigned short*)(ws + 3151872); // 8192 B
  unsigned short* fA1 = (unsigned short*)(ws + 3160064); // 32768 B
  unsigned short* fA2 = (unsigned short*)(ws + 3192832); // 32768 B (end 3225600)

  hipLaunchKernelGGL(aux_kernel, dim3(QKV_BLOCKS + 156), dim3(256), 0, stream,
                     wqkv, pw1, pw2, aw1, aw2, x, fW1, fW2, fA1, fA2, qkv);
  hipLaunchKernelGGL(main_kernel, dim3(128, 32), dim3(256), 0, stream,
                     pos, qkv, fW1, fW2, fA1, fA2, pb1, pb2, ab1, ab2, out);
}

// Round 11
// 214.436 us; speedup vs baseline: 1.2037x; 1.2037x over previous
//
#include <hip/hip_runtime.h>

// PointTransformerLayer fused kernel for MI355X (gfx950) — round 11.
// vs r10 (156us main: zero barriers/conflicts but occupancy 32% and inline
// weight-frag loads serialized the chain; everything scaled with occupancy):
//  * __launch_bounds__(256,4): 16 waves/CU target (cap 128 VGPR).
//  * hc loop FULLY unrolled + G4 interleaved per-mt (h2b liveness 16->8 regs)
//    => scheduler can hoist the 64 AF loads ahead of their MFMAs.
//  * aux reverted to r8's 512-block qkv (r10's 128-block version regressed).
// Dataflow unchanged from r10: j-tile wave ownership, C->B frag conversion
// in-register via v_permlane32_swap_b32, ONE barrier total (2KB LDS combine).
// Weights single bf16 (absmax 0.0156, threshold 0.088).
// ws: qkv@0 (3145728), fW1@3145728 (6144), fW2@3151872 (8192),
//     fA1@3160064 (32768), fA2@3192832 (32768); end 3225600 B.

typedef short short8 __attribute__((ext_vector_type(8)));
typedef float f32x4 __attribute__((ext_vector_type(4)));
typedef float f32x16 __attribute__((ext_vector_type(16)));
typedef unsigned int u32x4 __attribute__((ext_vector_type(4)));

union frag_u { short8 s; u32x4 u; };

__device__ __forceinline__ unsigned short f2bf(float x) {
  union { float f; unsigned int u; } a; a.f = x;
  unsigned int r = a.u + 0x7fffu + ((a.u >> 16) & 1u);  // RNE
  return (unsigned short)(r >> 16);
}
__device__ __forceinline__ unsigned int pk2(float a, float b) {  // a->lo16, b->hi16
  unsigned int r;
  asm("v_cvt_pk_bf16_f32 %0, %1, %2" : "=v"(r) : "v"(a), "v"(b));
  return r;
}

// ---------------- aux: qkv GEMM + single-plane weight A-frags ----------------
// A-frag (32x32x16): lane l holds A[row = mt*32 + (l&31)][k = kc*16 + (l>>5)*8 + e].
__device__ __forceinline__ void fill_frag(unsigned short* dst,
    const float* src, int Ksrc, int KC, int idx) {
  int e = idx & 7;
  int lane = (idx >> 3) & 63;
  int kc = (idx >> 9) % KC;
  int mt = idx / (512 * KC);
  int row = mt * 32 + (lane & 31);
  int k = kc * 16 + ((lane >> 5) << 3) + e;
  float v = (k < Ksrc) ? src[row * Ksrc + k] : 0.0f;
  dst[idx] = f2bf(v);
}

#define QKV_BLOCKS 512  // (bt 32) x (n-group 16), 8 rows each

__global__ void aux_kernel(const float* __restrict__ wqkv,
    const float* __restrict__ pw1, const float* __restrict__ pw2,
    const float* __restrict__ aw1, const float* __restrict__ aw2,
    const float* __restrict__ x,
    unsigned short* __restrict__ fW1, unsigned short* __restrict__ fW2,
    unsigned short* __restrict__ fA1, unsigned short* __restrict__ fA2,
    float* __restrict__ qkv) {
  int tid = threadIdx.x;
  if (blockIdx.x < QKV_BLOCKS) {  // ---- qkv: 8 rows of x per block ----
    __shared__ float xs[512];
    int bt = blockIdx.x >> 4, ng = blockIdx.x & 15;
    const float* xb = x + (bt * 128 + ng * 8) * 64;
    xs[tid] = xb[tid];
    xs[tid + 256] = xb[tid + 256];
    __syncthreads();
    if (tid < 192) {
      const float* wr_g = wqkv + tid * 64;
      float wr[64];
#pragma unroll
      for (int k = 0; k < 64; ++k) wr[k] = wr_g[k];
      float* qb = qkv + (size_t)(bt * 128 + ng * 8) * 192 + tid;
#pragma unroll
      for (int n = 0; n < 8; ++n) {
        float acc = 0.f;
#pragma unroll
        for (int k = 0; k < 64; ++k) acc += xs[n * 64 + k] * wr[k];
        qb[n * 192] = acc;
      }
    }
    return;
  }
  int gid = (blockIdx.x - QKV_BLOCKS) * 256 + tid;  // 39936 frag elems
  if (gid < 3072) { fill_frag(fW1, pw1, 34, 3, gid); return; }    // [64][34->48]
  gid -= 3072;
  if (gid < 4096) { fill_frag(fW2, pw2, 64, 4, gid); return; }    // [64][64]
  gid -= 4096;
  if (gid < 16384) { fill_frag(fA1, aw1, 64, 4, gid); return; }   // [256][64]
  gid -= 16384;
  fill_frag(fA2, aw2, 256, 16, gid);                              // [64][256]
}

// ---------------- main fused kernel ----------------
// C/D layout 32x32: col = l&31, row = (r&3) + 8*(r>>2) + 4*(l>>5).
// B-frag: lane l holds B[k = (l>>5)*8 + e][col = l&31], e = 0..7.
__device__ __forceinline__ f32x16 ld16(const float* p, int l) {
  f32x16 r;
#pragma unroll
  for (int q = 0; q < 4; ++q) {
    f32x4 v = *(const f32x4*)(p + 8 * q + ((l >> 5) << 2));
#pragma unroll
    for (int s = 0; s < 4; ++s) r[4 * q + s] = v[s];
  }
  return r;
}

// C-frag (32 rows = 2 k-chunks of 16) -> 2 B-frags, in-register.
// v_permlane32_swap_b32 vdst,vsrc: upper 32 lanes of vdst <-> lower 32 of vsrc.
__device__ __forceinline__ void c2b(f32x16 c, short8* out, bool relu) {
#pragma unroll
  for (int kk = 0; kk < 2; ++kk) {
    float a0 = c[8*kk+0], a1 = c[8*kk+1], a2 = c[8*kk+2], a3 = c[8*kk+3];
    float a4 = c[8*kk+4], a5 = c[8*kk+5], a6 = c[8*kk+6], a7 = c[8*kk+7];
    if (relu) {
      a0 = fmaxf(a0, 0.f); a1 = fmaxf(a1, 0.f); a2 = fmaxf(a2, 0.f); a3 = fmaxf(a3, 0.f);
      a4 = fmaxf(a4, 0.f); a5 = fmaxf(a5, 0.f); a6 = fmaxf(a6, 0.f); a7 = fmaxf(a7, 0.f);
    }
    unsigned u0 = pk2(a0, a1), u1 = pk2(a2, a3), u2 = pk2(a4, a5), u3 = pk2(a6, a7);
    asm("v_permlane32_swap_b32 %0, %1" : "+v"(u0), "+v"(u2));
    asm("v_permlane32_swap_b32 %0, %1" : "+v"(u1), "+v"(u3));
    frag_u fu; fu.u[0] = u0; fu.u[1] = u1; fu.u[2] = u2; fu.u[3] = u3;
    out[kk] = fu.s;
  }
}

#define MFMA32(acc, av, bv) \
  acc = __builtin_amdgcn_mfma_f32_32x32x16_bf16(av, bv, acc, 0, 0, 0)
#define AF(ptr, idx) (*(const short8*)((ptr) + (size_t)(idx) * 512 + (size_t)l * 8))

__global__ __launch_bounds__(256, 4) void main_kernel(
    const float* __restrict__ pos, const float* __restrict__ qkv,
    const unsigned short* __restrict__ fW1, const unsigned short* __restrict__ fW2,
    const unsigned short* __restrict__ fA1, const unsigned short* __restrict__ fA2,
    const float* __restrict__ pb1, const float* __restrict__ pb2,
    const float* __restrict__ ab1, const float* __restrict__ ab2,
    float* __restrict__ out) {
  __shared__ float red[512];  // [wave][pd 64 | pn 64]
  const int i = blockIdx.x, bt = blockIdx.y;
  const int tid = threadIdx.x;
  const int w = tid >> 6, l = tid & 63;     // wave w owns j-tile w
  const int lc = l & 31, h5 = l >> 5;
  const int j = w * 32 + lc;

  // ---- X1 B-frags in registers: f = c*17+jj (34 real, 48 padded) ----
  short8 x1f[3];
#pragma unroll
  for (int kc = 0; kc < 3; ++kc) {
    frag_u fu;
#pragma unroll
    for (int wo = 0; wo < 4; ++wo) {
      float v0 = 0.f, v1 = 0.f;
      int f0 = kc * 16 + h5 * 8 + 2 * wo;
      if (f0 < 34) {
        int c = (f0 >= 17) ? 1 : 0;
        const float* ps = pos + (((bt * 17 + (f0 - 17 * c)) * 3 + c) << 7);
        v0 = ps[i] - ps[j];
      }
      int f1 = f0 + 1;
      if (f1 < 34) {
        int c = (f1 >= 17) ? 1 : 0;
        const float* ps = pos + (((bt * 17 + (f1 - 17 * c)) * 3 + c) << 7);
        v1 = ps[i] - ps[j];
      }
      fu.u[wo] = pk2(v0, v1);
    }
    x1f[kc] = fu.s;
  }

  // ---- G1: H1 = relu(W1 @ X1^T + b1), C-frags -> B-frags in-register ----
  short8 h1b[4];
#pragma unroll
  for (int mt = 0; mt < 2; ++mt) {
    f32x16 acc = ld16(pb1 + mt * 32, l);
#pragma unroll
    for (int kc = 0; kc < 3; ++kc) MFMA32(acc, AF(fW1, mt * 3 + kc), x1f[kc]);
    c2b(acc, &h1b[2 * mt], true);
  }

  // ---- G2 + E-stage: E = W2 @ H1^T + b2; U/vp in-register ----
  unsigned vpk[16];
  short8 ub[4];
  const float* qkv_bt = qkv + (size_t)(bt * 128) * 192;
  const float* rp = qkv_bt + j * 192;
#pragma unroll
  for (int mt = 0; mt < 2; ++mt) {
    f32x16 e = ld16(pb2 + mt * 32, l);
#pragma unroll
    for (int kc = 0; kc < 4; ++kc) MFMA32(e, AF(fW2, mt * 4 + kc), h1b[kc]);
    f32x16 qv = ld16(qkv_bt + i * 192 + mt * 32, l);
    f32x16 kk = ld16(rp + 64 + mt * 32, l);
    f32x16 vv = ld16(rp + 128 + mt * 32, l);
    f32x16 u;
#pragma unroll
    for (int r = 0; r < 16; ++r) u[r] = qv[r] - kk[r] + e[r];
#pragma unroll
    for (int s = 0; s < 8; ++s)
      vpk[mt * 8 + s] = pk2(vv[2 * s] + e[2 * s], vv[2 * s + 1] + e[2 * s + 1]);
    c2b(u, &ub[2 * mt], false);
  }

  // ---- G3/G4 over 4 h-chunks of 64: fully unrolled, G4 interleaved per mt ----
  // G4 k-chunk kc' = 2*mt + q2 is produced by mt's c2b slot hb[q2].
  f32x16 s0 = ld16(ab2, l), s1 = ld16(ab2 + 32, l);
#pragma unroll
  for (int hc = 0; hc < 4; ++hc) {
#pragma unroll
    for (int mt = 0; mt < 2; ++mt) {
      f32x16 h = ld16(ab1 + hc * 64 + mt * 32, l);
#pragma unroll
      for (int kc = 0; kc < 4; ++kc) MFMA32(h, AF(fA1, (hc * 2 + mt) * 4 + kc), ub[kc]);
      short8 hb[2];
      c2b(h, hb, true);
#pragma unroll
      for (int q2 = 0; q2 < 2; ++q2) {
        MFMA32(s0, AF(fA2, hc * 4 + mt * 2 + q2), hb[q2]);
        MFMA32(s1, AF(fA2, 16 + hc * 4 + mt * 2 + q2), hb[q2]);
      }
    }
  }

  // ---- epilogue: softmax over j (exp-safe) + weighted vp sum ----
#pragma unroll
  for (int mt = 0; mt < 2; ++mt) {
    f32x16 sc = mt ? s1 : s0;
#pragma unroll
    for (int pi = 0; pi < 8; ++pi) {
      int r0 = 2 * pi;
      float x0 = __expf(sc[r0]), x1 = __expf(sc[r0 + 1]);
      unsigned pv = vpk[mt * 8 + pi];
      float v0 = __uint_as_float(pv << 16);
      float v1 = __uint_as_float(pv & 0xffff0000u);
      float pd0 = x0, pn0 = x0 * v0;
      float pd1 = x1, pn1 = x1 * v1;
#pragma unroll
      for (int m = 1; m <= 16; m <<= 1) {
        pd0 += __shfl_xor(pd0, m); pn0 += __shfl_xor(pn0, m);
        pd1 += __shfl_xor(pd1, m); pn1 += __shfl_xor(pn1, m);
      }
      if (lc == 0) {
        int d0 = mt * 32 + (r0 & 3) + 8 * (r0 >> 2) + 4 * h5;
        red[w * 128 + d0] = pd0;          red[w * 128 + 64 + d0] = pn0;
        red[w * 128 + d0 + 1] = pd1;      red[w * 128 + 64 + d0 + 1] = pn1;
      }
    }
  }
  __syncthreads();
  if (tid < 64) {
    float den = red[tid] + red[128 + tid] + red[256 + tid] + red[384 + tid];
    float num = red[64 + tid] + red[192 + tid] + red[320 + tid] + red[448 + tid];
    out[(bt * 128 + i) * 64 + tid] = num / den;
  }
}

extern "C" void kernel_launch(void* const* d_in, const int* in_sizes, int n_in,
                              void* d_out, int out_size, void* d_ws, size_t ws_size,
                              hipStream_t stream) {
  const float* x    = (const float*)d_in[0];
  const float* pos  = (const float*)d_in[1];
  const float* wqkv = (const float*)d_in[2];
  const float* pw1  = (const float*)d_in[3];
  const float* pb1  = (const float*)d_in[4];
  const float* pw2  = (const float*)d_in[5];
  const float* pb2  = (const float*)d_in[6];
  const float* aw1  = (const float*)d_in[7];
  const float* ab1  = (const float*)d_in[8];
  const float* aw2  = (const float*)d_in[9];
  const float* ab2  = (const float*)d_in[10];
  float* out = (float*)d_out;
  char* ws = (char*)d_ws;

  float* qkv = (float*)ws;                               // 3145728 B
  unsigned short* fW1 = (unsigned short*)(ws + 3145728); // 6144 B
  unsigned short* fW2 = (unsigned short*)(ws + 3151872); // 8192 B
  unsigned short* fA1 = (unsigned short*)(ws + 3160064); // 32768 B
  unsigned short* fA2 = (unsigned short*)(ws + 3192832); // 32768 B (end 3225600)

  hipLaunchKernelGGL(aux_kernel, dim3(QKV_BLOCKS + 156), dim3(256), 0, stream,
                     wqkv, pw1, pw2, aw1, aw2, x, fW1, fW2, fA1, fA2, qkv);
  hipLaunchKernelGGL(main_kernel, dim3(128, 32), dim3(256), 0, stream,
                     pos, qkv, fW1, fW2, fA1, fA2, pb1, pb2, ab1, ab2, out);
}